// Round 5
// baseline (59.883 us; speedup 1.0000x reference)
//
#include <hip/hip_runtime.h>

// Chamfer distance, B=4, N=M=8192, fp32 points in R^3 — MFMA formulation.
//
// R3 post-mortem: scalar-VALU version is issue-bound at ~48 us (occupancy and
// LDS changes both null). Switch pipes: d_ij = |x|^2 - 2 x.y + |y|^2 via
// v_mfma_f32_32x32x16_bf16 with split-bf16 operands (x ~ xh + xl), using 13
// of 16 K-slots:
//   k0-2 : xh_d   * (-2yh_d)      k3-5 : xh_d * (-2yl_d)
//   k6-8 : xl_d   * (-2yh_d)      (xl*yl dropped: ~2^-18 relative)
//   k9-10: 1 * (ch, cl)           (|y|^2 split)
//   k11-12: (sxh, sxl) * 1        (|x|^2 split)
// One MFMA = 32x32 distance tile; per-tile C = 0 (separate C/D regs);
// min-combined into best[16] via v_min3_f32 over j-tile pairs.
// A layout: lane&31 = row, k = (lane>>5)*8 + elem.  B: lane&31 = col, same k.
// C/D (m74/m101): col = lane&31, row = (reg&3) + 8*(reg>>2) + 4*(lane>>5).
// Cross-block combine over j-segments: atomicMin on monotone float keys.

#define BATCH 4
#define NPTS 8192
#define TPB 512                                   // 8 waves
#define WAVES 8
#define ROWS_PER_WAVE 32
#define ROWS_PER_BLOCK (WAVES * ROWS_PER_WAVE)    // 256
#define ROWBLOCKS (NPTS / ROWS_PER_BLOCK)         // 32
#define SEGS 8
#define SEGLEN (NPTS / SEGS)                      // 1024
#define CHUNK 512
#define CHUNKS (SEGLEN / CHUNK)                   // 2
#define JT_PER_CHUNK (CHUNK / 32)                 // 16

typedef __attribute__((ext_vector_type(8))) short bf16x8;
typedef __attribute__((ext_vector_type(16))) float f32x16;

union FragU { int4 i4; bf16x8 v; };

__device__ inline unsigned short bf16_rne(float f) {
    unsigned int u = __float_as_uint(f);
    return (unsigned short)((u + 0x7FFFu + ((u >> 16) & 1u)) >> 16);
}
__device__ inline float bf16_f32(unsigned short h) {
    return __uint_as_float(((unsigned int)h) << 16);
}
__device__ inline unsigned int pack2(unsigned int lo, unsigned int hi) {
    return (lo & 0xFFFFu) | (hi << 16);
}

__global__ __launch_bounds__(TPB, 4) void chamfer_mfma_kernel(
    const float* __restrict__ xyz1,
    const float* __restrict__ xyz2,
    unsigned int* __restrict__ bits1,
    unsigned int* __restrict__ bits2)
{
    const int blk = blockIdx.x;
    const int seg = blk & (SEGS - 1);
    const int rb  = (blk >> 3) & (ROWBLOCKS - 1);
    const int b   = (blk >> 8) & (BATCH - 1);
    const int dir = blk >> 10;

    const float* pa = dir ? xyz2 : xyz1;           // rows (query)
    const float* pb = dir ? xyz1 : xyz2;           // cols (reference)
    unsigned int* best_bits = dir ? bits2 : bits1;

    const int t    = threadIdx.x;
    const int lane = t & 63;
    const int wave = t >> 6;
    const int half = lane >> 5;
    const int l31  = lane & 31;

    __shared__ int4 sb0[CHUNK];   // B-frag for lanes 0-31 (k slots 0-7)
    __shared__ int4 sb1[CHUNK];   // B-frag for lanes 32-63 (k slots 8-15)

    // ---- A fragment for this wave's 32 rows (built once) ----
    const int rowbase = rb * ROWS_PER_BLOCK + wave * ROWS_PER_WAVE;
    FragU afrag;
    {
        const float* px = pa + ((size_t)b * NPTS + rowbase + l31) * 3;
        const float x0 = px[0], x1 = px[1], x2 = px[2];
        const unsigned short xh0 = bf16_rne(x0);
        const unsigned short xh1 = bf16_rne(x1);
        const unsigned short xh2 = bf16_rne(x2);
        const unsigned short xl0 = bf16_rne(x0 - bf16_f32(xh0));
        const unsigned short xl1 = bf16_rne(x1 - bf16_f32(xh1));
        const unsigned short xl2 = bf16_rne(x2 - bf16_f32(xh2));
        const float sx = x0 * x0 + x1 * x1 + x2 * x2;
        const unsigned short sxh = bf16_rne(sx);
        const unsigned short sxl = bf16_rne(sx - bf16_f32(sxh));
        const unsigned short one = 0x3F80;
        int4 lo, hi;
        lo.x = pack2(xh0, xh1); lo.y = pack2(xh2, xh0);
        lo.z = pack2(xh1, xh2); lo.w = pack2(xl0, xl1);
        hi.x = pack2(xl2, one); hi.y = pack2(one, sxh);
        hi.z = pack2(sxl, 0u);  hi.w = 0;
        afrag.i4 = half ? hi : lo;
    }

    f32x16 best;
#pragma unroll
    for (int r = 0; r < 16; ++r) best[r] = __builtin_inff();
    const f32x16 zero = {0.0f, 0.0f, 0.0f, 0.0f, 0.0f, 0.0f, 0.0f, 0.0f,
                         0.0f, 0.0f, 0.0f, 0.0f, 0.0f, 0.0f, 0.0f, 0.0f};

    const float* ybase = pb + ((size_t)b * NPTS + (size_t)seg * SEGLEN) * 3;

    for (int c = 0; c < CHUNKS; ++c) {
        __syncthreads();          // previous chunk fully consumed
        {
            // stage one y-point per thread as prepacked B-fragments
            const float* py = ybase + ((size_t)c * CHUNK + t) * 3;
            const float y0 = py[0], y1 = py[1], y2 = py[2];
            const float g0 = -2.0f * y0, g1 = -2.0f * y1, g2 = -2.0f * y2;
            const unsigned short gh0 = bf16_rne(g0);
            const unsigned short gh1 = bf16_rne(g1);
            const unsigned short gh2 = bf16_rne(g2);
            const unsigned short gl0 = bf16_rne(g0 - bf16_f32(gh0));
            const unsigned short gl1 = bf16_rne(g1 - bf16_f32(gh1));
            const unsigned short gl2 = bf16_rne(g2 - bf16_f32(gh2));
            const float cy = y0 * y0 + y1 * y1 + y2 * y2;
            const unsigned short ch = bf16_rne(cy);
            const unsigned short cl = bf16_rne(cy - bf16_f32(ch));
            const unsigned short one = 0x3F80;
            int4 t0, t1;
            t0.x = pack2(gh0, gh1); t0.y = pack2(gh2, gl0);
            t0.z = pack2(gl1, gl2); t0.w = pack2(gh0, gh1);
            t1.x = pack2(gh2, ch);  t1.y = pack2(cl, one);
            t1.z = pack2(one, 0u);  t1.w = 0;
            sb0[t] = t0;
            sb1[t] = t1;
        }
        __syncthreads();

        const int4* src = half ? sb1 : sb0;
#pragma unroll 2
        for (int jt = 0; jt < JT_PER_CHUNK; jt += 2) {
            FragU bf0, bf1;
            bf0.i4 = src[jt * 32 + l31];
            bf1.i4 = src[(jt + 1) * 32 + l31];
            f32x16 d0 = __builtin_amdgcn_mfma_f32_32x32x16_bf16(afrag.v, bf0.v, zero, 0, 0, 0);
            f32x16 d1 = __builtin_amdgcn_mfma_f32_32x32x16_bf16(afrag.v, bf1.v, zero, 0, 0, 0);
#pragma unroll
            for (int r = 0; r < 16; ++r)
                best[r] = fminf(best[r], fminf(d0[r], d1[r]));   // v_min3_f32
        }
    }

    // ---- min across the 32 lanes of each half (cols) ----
#pragma unroll
    for (int r = 0; r < 16; ++r) {
        float v = best[r];
        v = fminf(v, __shfl_xor(v, 1, 64));
        v = fminf(v, __shfl_xor(v, 2, 64));
        v = fminf(v, __shfl_xor(v, 4, 64));
        v = fminf(v, __shfl_xor(v, 8, 64));
        v = fminf(v, __shfl_xor(v, 16, 64));
        best[r] = v;
    }

    // ---- one atomic per (row, half): row = (r&3) + 8*(r>>2) + 4*half ----
#pragma unroll
    for (int r = 0; r < 16; ++r) {
        if (l31 == r) {
            const int row = rowbase + (r & 3) + 8 * (r >> 2) + (half << 2);
            const unsigned int u = __float_as_uint(best[r]);
            const unsigned int key = u ^ ((u >> 31) ? 0xFFFFFFFFu : 0x80000000u);
            atomicMin(&best_bits[(size_t)b * NPTS + row], key);
        }
    }
}

__device__ inline float key_decode(unsigned int key) {
    const unsigned int u = (key & 0x80000000u) ? (key ^ 0x80000000u) : ~key;
    return __uint_as_float(u);
}

__global__ __launch_bounds__(1024) void reduce_kernel(
    const unsigned int* __restrict__ u1,
    const unsigned int* __restrict__ u2,
    float* __restrict__ out)
{
    const int n4 = BATCH * NPTS / 4;
    const uint4* v1 = (const uint4*)u1;
    const uint4* v2 = (const uint4*)u2;
    double s1 = 0.0, s2 = 0.0;
    for (int i = threadIdx.x; i < n4; i += blockDim.x) {
        const uint4 a = v1[i];
        const uint4 c = v2[i];
        s1 += (double)key_decode(a.x) + (double)key_decode(a.y)
            + (double)key_decode(a.z) + (double)key_decode(a.w);
        s2 += (double)key_decode(c.x) + (double)key_decode(c.y)
            + (double)key_decode(c.z) + (double)key_decode(c.w);
    }
    for (int off = 32; off > 0; off >>= 1) {
        s1 += __shfl_down(s1, off, 64);
        s2 += __shfl_down(s2, off, 64);
    }
    __shared__ double l1[16], l2[16];
    const int wave = threadIdx.x >> 6;
    if ((threadIdx.x & 63) == 0) { l1[wave] = s1; l2[wave] = s2; }
    __syncthreads();
    if (threadIdx.x == 0) {
        double t1 = 0.0, t2 = 0.0;
        const int nw = blockDim.x >> 6;
        for (int w = 0; w < nw; ++w) { t1 += l1[w]; t2 += l2[w]; }
        const double n = (double)(BATCH * NPTS);
        out[0] = (float)(t1 / n + t2 / n);
    }
}

extern "C" void kernel_launch(void* const* d_in, const int* in_sizes, int n_in,
                              void* d_out, int out_size, void* d_ws, size_t ws_size,
                              hipStream_t stream) {
    const float* xyz1 = (const float*)d_in[0];
    const float* xyz2 = (const float*)d_in[1];
    float* out = (float*)d_out;
    unsigned int* u1 = (unsigned int*)d_ws;
    unsigned int* u2 = u1 + BATCH * NPTS;

    hipMemsetAsync(u1, 0xFF, 2 * BATCH * NPTS * sizeof(unsigned int), stream);

    const int grid = 2 * BATCH * ROWBLOCKS * SEGS;   // 2048 blocks
    chamfer_mfma_kernel<<<grid, TPB, 0, stream>>>(xyz1, xyz2, u1, u2);

    reduce_kernel<<<1, 1024, 0, stream>>>(u1, u2, out);
}

// Round 6
// 37.090 us; speedup vs baseline: 1.6145x; 1.6145x over previous
//
#include <hip/hip_runtime.h>

// Chamfer distance, B=4, N=M=8192, fp32 in R^3 — MFMA, role-swapped.
//
// d_ij = |y_j|^2 - 2 x_i.y_j + |x_i|^2 via v_mfma_f32_32x32x16_bf16,
// split-bf16 (13 of 16 K-slots; xl*yl dropped ~2^-18).
// A operand = STREAMED y rows (from LDS), B = FIXED x cols (4 frags/wave).
// C/D: col=lane&31, row=(reg&3)+8*(reg>>2)+4*half  =>  a lane's 16 regs are
// 16 rows of ONE column => row-min = within-lane min3 tree (8 min3/MFMA)
// accumulated into 1 scalar/lane. Epilogue = 1 shuffle + 1 atomic per frag.
// Fragments prepacked by a tiny kernel into ws (both roles, both arrays).
// R4 post-mortem: VGPR_Count=48 => AGPR shuttling around fminf; fix via
// small live set + asm VGPR pin + launch_bounds(256,4) (128-VGPR cap).

#define BATCH 4
#define NPTS 8192
#define TPB 256
#define NFRAG 4
#define COLS_PER_WAVE 128                 // NFRAG * 32
#define COLS_PER_BLOCK 512                // 4 waves
#define XBLKS (NPTS / COLS_PER_BLOCK)     // 16
#define YSEGS 8
#define YSEG (NPTS / YSEGS)               // 1024
#define CHUNK 512
#define NCHUNK (YSEG / CHUNK)             // 2
#define JT (CHUNK / 32)                   // 16

typedef __attribute__((ext_vector_type(8))) short bf16x8;
typedef __attribute__((ext_vector_type(16))) float f32x16;
union FragU { int4 i4; bf16x8 v; };

__device__ inline unsigned short bf16_rne(float f) {
    unsigned int u = __float_as_uint(f);
    return (unsigned short)((u + 0x7FFFu + ((u >> 16) & 1u)) >> 16);
}
__device__ inline float bf16_f32(unsigned short h) {
    return __uint_as_float(((unsigned int)h) << 16);
}
__device__ inline unsigned int pack2(unsigned int lo, unsigned int hi) {
    return (lo & 0xFFFFu) | (hi << 16);
}

// ---- prepack: per point, row-role frag (y-side) + col-role frag (x-side) ----
__global__ __launch_bounds__(256) void prepack_kernel(
    const float* __restrict__ xyz1, const float* __restrict__ xyz2,
    int4* __restrict__ rowpack, int4* __restrict__ colpack)
{
    const int id  = blockIdx.x * 256 + threadIdx.x;    // [0, 65536)
    const int arr = id >> 15;
    const int rem = id & 32767;                         // b*8192+n
    const float* p = (arr ? xyz2 : xyz1) + (size_t)rem * 3;
    const float x0 = p[0], x1 = p[1], x2 = p[2];

    const unsigned short h0 = bf16_rne(x0), h1 = bf16_rne(x1), h2 = bf16_rne(x2);
    const unsigned short l0 = bf16_rne(x0 - bf16_f32(h0));
    const unsigned short l1 = bf16_rne(x1 - bf16_f32(h1));
    const unsigned short l2 = bf16_rne(x2 - bf16_f32(h2));
    const float s = x0 * x0 + x1 * x1 + x2 * x2;
    const unsigned short sh = bf16_rne(s);
    const unsigned short sl = bf16_rne(s - bf16_f32(sh));
    const unsigned short one = 0x3F80;

    // row role: [h0,h1,h2,h0,h1,h2,l0,l1 | l2,one,one,sh,sl,0,0,0]
    int4 rlo, rhi;
    rlo.x = pack2(h0, h1); rlo.y = pack2(h2, h0);
    rlo.z = pack2(h1, h2); rlo.w = pack2(l0, l1);
    rhi.x = pack2(l2, one); rhi.y = pack2(one, sh);
    rhi.z = pack2(sl, 0u);  rhi.w = 0;
    rowpack[2 * id]     = rlo;
    rowpack[2 * id + 1] = rhi;

    // col role: g=-2x: [gh0,gh1,gh2,gl0,gl1,gl2,gh0,gh1 | gh2,sh,sl,one,one,0,0,0]
    const float g0 = -2.0f * x0, g1 = -2.0f * x1, g2 = -2.0f * x2;
    const unsigned short gh0 = bf16_rne(g0), gh1 = bf16_rne(g1), gh2 = bf16_rne(g2);
    const unsigned short gl0 = bf16_rne(g0 - bf16_f32(gh0));
    const unsigned short gl1 = bf16_rne(g1 - bf16_f32(gh1));
    const unsigned short gl2 = bf16_rne(g2 - bf16_f32(gh2));
    int4 clo, chi;
    clo.x = pack2(gh0, gh1); clo.y = pack2(gh2, gl0);
    clo.z = pack2(gl1, gl2); clo.w = pack2(gh0, gh1);
    chi.x = pack2(gh2, sh);  chi.y = pack2(sl, one);
    chi.z = pack2(one, 0u);  chi.w = 0;
    colpack[2 * id]     = clo;
    colpack[2 * id + 1] = chi;
}

__device__ inline float red16(float cb, const f32x16& d) {
    const float m0 = fminf(fminf(d[0],  d[1]),  d[2]);
    const float m1 = fminf(fminf(d[3],  d[4]),  d[5]);
    const float m2 = fminf(fminf(d[6],  d[7]),  d[8]);
    const float m3 = fminf(fminf(d[9],  d[10]), d[11]);
    const float m4 = fminf(fminf(d[12], d[13]), d[14]);
    const float u0 = fminf(fminf(m0, m1), m2);
    const float u1 = fminf(fminf(m3, m4), d[15]);
    return fminf(fminf(cb, u0), u1);
}

__global__ __launch_bounds__(TPB, 4) void chamfer_main(
    const int4* __restrict__ rowpack,
    const int4* __restrict__ colpack,
    unsigned int* __restrict__ keys)
{
    const int blk  = blockIdx.x;
    const int seg  = blk & (YSEGS - 1);
    const int xblk = (blk >> 3) & (XBLKS - 1);
    const int b    = (blk >> 7) & (BATCH - 1);
    const int dir  = blk >> 9;
    const int arrB = dir;        // cols = array whose dist we output
    const int arrA = dir ^ 1;    // rows = the other array, streamed

    const int t = threadIdx.x, lane = t & 63, wave = t >> 6;
    const int half = lane >> 5, l31 = lane & 31;

    __shared__ int4 sb0[CHUNK];   // half0 row-frags
    __shared__ int4 sb1[CHUNK];   // half1 row-frags

    // fixed B fragments: 4 x-col tiles per wave
    const int xbase = xblk * COLS_PER_BLOCK + wave * COLS_PER_WAVE;
    const size_t cb_idx = ((size_t)(arrB * BATCH + b) * NPTS + xbase) * 2;
    FragU bf0, bf1, bf2, bf3;
    bf0.i4 = colpack[cb_idx + (size_t)(0 * 32 + l31) * 2 + half];
    bf1.i4 = colpack[cb_idx + (size_t)(1 * 32 + l31) * 2 + half];
    bf2.i4 = colpack[cb_idx + (size_t)(2 * 32 + l31) * 2 + half];
    bf3.i4 = colpack[cb_idx + (size_t)(3 * 32 + l31) * 2 + half];

    float cb[NFRAG];
#pragma unroll
    for (int f = 0; f < NFRAG; ++f) cb[f] = __builtin_inff();
    const f32x16 zero = {0.0f, 0.0f, 0.0f, 0.0f, 0.0f, 0.0f, 0.0f, 0.0f,
                         0.0f, 0.0f, 0.0f, 0.0f, 0.0f, 0.0f, 0.0f, 0.0f};

    const size_t rbase = ((size_t)(arrA * BATCH + b) * NPTS + (size_t)seg * YSEG) * 2;

    for (int c = 0; c < NCHUNK; ++c) {
        __syncthreads();
        {
            // copy 512 prepacked row-frags (2 pts / thread, 64B coalesced)
            const int4* src = rowpack + rbase + (size_t)c * CHUNK * 2 + (size_t)t * 4;
            const int4 a0 = src[0], a1 = src[1], a2 = src[2], a3 = src[3];
            sb0[2 * t]     = a0;  sb1[2 * t]     = a1;
            sb0[2 * t + 1] = a2;  sb1[2 * t + 1] = a3;
        }
        __syncthreads();

        const int4* asrc = half ? sb1 : sb0;
#pragma unroll 2
        for (int jt = 0; jt < JT; ++jt) {
            FragU af; af.i4 = asrc[jt * 32 + l31];
            f32x16 d0 = __builtin_amdgcn_mfma_f32_32x32x16_bf16(af.v, bf0.v, zero, 0, 0, 0);
            f32x16 d1 = __builtin_amdgcn_mfma_f32_32x32x16_bf16(af.v, bf1.v, zero, 0, 0, 0);
            f32x16 d2 = __builtin_amdgcn_mfma_f32_32x32x16_bf16(af.v, bf2.v, zero, 0, 0, 0);
            f32x16 d3 = __builtin_amdgcn_mfma_f32_32x32x16_bf16(af.v, bf3.v, zero, 0, 0, 0);
            // pin results to arch VGPRs so min3 doesn't round-trip AGPRs
            asm volatile("" :: "v"(d0));
            asm volatile("" :: "v"(d1));
            asm volatile("" :: "v"(d2));
            asm volatile("" :: "v"(d3));
            cb[0] = red16(cb[0], d0);
            cb[1] = red16(cb[1], d1);
            cb[2] = red16(cb[2], d2);
            cb[3] = red16(cb[3], d3);
        }
    }

    // epilogue: combine the two halves (same cols), one atomic per frag
    unsigned int* ok = keys + ((size_t)dir * BATCH + b) * NPTS + xbase;
#pragma unroll
    for (int f = 0; f < NFRAG; ++f) {
        const float v = fminf(cb[f], __shfl_xor(cb[f], 32, 64));
        if (half == 0) {
            const unsigned int u = __float_as_uint(v);
            const unsigned int key = u ^ ((u >> 31) ? 0xFFFFFFFFu : 0x80000000u);
            atomicMin(&ok[f * 32 + l31], key);
        }
    }
}

__device__ inline float key_decode(unsigned int key) {
    const unsigned int u = (key & 0x80000000u) ? (key ^ 0x80000000u) : ~key;
    return __uint_as_float(u);
}

__global__ __launch_bounds__(1024) void reduce_kernel(
    const unsigned int* __restrict__ u1,
    const unsigned int* __restrict__ u2,
    float* __restrict__ out)
{
    const int n4 = BATCH * NPTS / 4;
    const uint4* v1 = (const uint4*)u1;
    const uint4* v2 = (const uint4*)u2;
    double s1 = 0.0, s2 = 0.0;
    for (int i = threadIdx.x; i < n4; i += blockDim.x) {
        const uint4 a = v1[i];
        const uint4 c = v2[i];
        s1 += (double)key_decode(a.x) + (double)key_decode(a.y)
            + (double)key_decode(a.z) + (double)key_decode(a.w);
        s2 += (double)key_decode(c.x) + (double)key_decode(c.y)
            + (double)key_decode(c.z) + (double)key_decode(c.w);
    }
    for (int off = 32; off > 0; off >>= 1) {
        s1 += __shfl_down(s1, off, 64);
        s2 += __shfl_down(s2, off, 64);
    }
    __shared__ double l1[16], l2[16];
    const int wave = threadIdx.x >> 6;
    if ((threadIdx.x & 63) == 0) { l1[wave] = s1; l2[wave] = s2; }
    __syncthreads();
    if (threadIdx.x == 0) {
        double t1 = 0.0, t2 = 0.0;
        const int nw = blockDim.x >> 6;
        for (int w = 0; w < nw; ++w) { t1 += l1[w]; t2 += l2[w]; }
        const double n = (double)(BATCH * NPTS);
        out[0] = (float)(t1 / n + t2 / n);
    }
}

extern "C" void kernel_launch(void* const* d_in, const int* in_sizes, int n_in,
                              void* d_out, int out_size, void* d_ws, size_t ws_size,
                              hipStream_t stream) {
    const float* xyz1 = (const float*)d_in[0];
    const float* xyz2 = (const float*)d_in[1];
    float* out = (float*)d_out;

    int4* rowpack = (int4*)d_ws;                       // 2*65536 int4 = 2 MB
    int4* colpack = rowpack + 2 * 65536;               // 2 MB
    unsigned int* keys = (unsigned int*)(colpack + 2 * 65536);   // 256 KB

    hipMemsetAsync(keys, 0xFF, 2 * BATCH * NPTS * sizeof(unsigned int), stream);
    prepack_kernel<<<256, 256, 0, stream>>>(xyz1, xyz2, rowpack, colpack);

    chamfer_main<<<2 * BATCH * XBLKS * YSEGS, TPB, 0, stream>>>(rowpack, colpack, keys);

    reduce_kernel<<<1, 1024, 0, stream>>>(keys, keys + BATCH * NPTS, out);
}

// Round 7
// 33.455 us; speedup vs baseline: 1.7900x; 1.1087x over previous
//
#include <hip/hip_runtime.h>

// Chamfer distance, B=4, N=M=8192, fp32 in R^3 — MFMA, role-swapped.
//
// d_ij = |y_j|^2 - 2 x_i.y_j + |x_i|^2 via v_mfma_f32_32x32x16_bf16,
// split-bf16 (13 of 16 K-slots; xl*yl dropped ~2^-18).
// A = STREAMED y rows (LDS), B = FIXED x cols (NFRAG frags/wave).
// C/D: col=lane&31, row=(reg&3)+8*(reg>>2)+4*half => lane's 16 regs = 16 rows
// of ONE column => row-min = in-lane min3 tree (8 min3/MFMA) into 1 scalar.
// R6: NFRAG 4->2 + launch_bounds(256,8) + grid 2048 => 8 waves/SIMD
// (R5 était 4 waves/SIMD; MFMA floor is 6.8 us, need occupancy to overlap
// mfma->min3 dependency chains). Memset folded into prepack; reduce is
// 8 blocks + last-block finalize (atomicExch partials -> coherent point).

#define BATCH 4
#define NPTS 8192
#define TPB 256
#define NFRAG 2
#define COLS_PER_WAVE 64                  // NFRAG * 32
#define COLS_PER_BLOCK 256                // 4 waves
#define XBLKS (NPTS / COLS_PER_BLOCK)     // 32
#define YSEGS 8
#define YSEG (NPTS / YSEGS)               // 1024
#define CHUNK 512
#define NCHUNK (YSEG / CHUNK)             // 2
#define JT (CHUNK / 32)                   // 16

typedef __attribute__((ext_vector_type(8))) short bf16x8;
typedef __attribute__((ext_vector_type(16))) float f32x16;
union FragU { int4 i4; bf16x8 v; };

__device__ inline unsigned short bf16_rne(float f) {
    unsigned int u = __float_as_uint(f);
    return (unsigned short)((u + 0x7FFFu + ((u >> 16) & 1u)) >> 16);
}
__device__ inline float bf16_f32(unsigned short h) {
    return __uint_as_float(((unsigned int)h) << 16);
}
__device__ inline unsigned int pack2(unsigned int lo, unsigned int hi) {
    return (lo & 0xFFFFu) | (hi << 16);
}

// ---- prepack: frag both roles; also init keys + zero the reduce counter ----
__global__ __launch_bounds__(256) void prepack_kernel(
    const float* __restrict__ xyz1, const float* __restrict__ xyz2,
    int4* __restrict__ rowpack, int4* __restrict__ colpack,
    unsigned int* __restrict__ keys, unsigned int* __restrict__ counter)
{
    const int id  = blockIdx.x * 256 + threadIdx.x;    // [0, 65536)
    const int arr = id >> 15;
    const int rem = id & 32767;                         // b*8192+n
    const float* p = (arr ? xyz2 : xyz1) + (size_t)rem * 3;
    const float x0 = p[0], x1 = p[1], x2 = p[2];

    keys[id] = 0xFFFFFFFFu;                             // exactly 2*B*N threads
    if (id == 0) *counter = 0;

    const unsigned short h0 = bf16_rne(x0), h1 = bf16_rne(x1), h2 = bf16_rne(x2);
    const unsigned short l0 = bf16_rne(x0 - bf16_f32(h0));
    const unsigned short l1 = bf16_rne(x1 - bf16_f32(h1));
    const unsigned short l2 = bf16_rne(x2 - bf16_f32(h2));
    const float s = x0 * x0 + x1 * x1 + x2 * x2;
    const unsigned short sh = bf16_rne(s);
    const unsigned short sl = bf16_rne(s - bf16_f32(sh));
    const unsigned short one = 0x3F80;

    // row role: [h0,h1,h2,h0,h1,h2,l0,l1 | l2,one,one,sh,sl,0,0,0]
    int4 rlo, rhi;
    rlo.x = pack2(h0, h1); rlo.y = pack2(h2, h0);
    rlo.z = pack2(h1, h2); rlo.w = pack2(l0, l1);
    rhi.x = pack2(l2, one); rhi.y = pack2(one, sh);
    rhi.z = pack2(sl, 0u);  rhi.w = 0;
    rowpack[2 * id]     = rlo;
    rowpack[2 * id + 1] = rhi;

    // col role: g=-2x: [gh0,gh1,gh2,gl0,gl1,gl2,gh0,gh1 | gh2,sh,sl,one,one,0,0,0]
    const float g0 = -2.0f * x0, g1 = -2.0f * x1, g2 = -2.0f * x2;
    const unsigned short gh0 = bf16_rne(g0), gh1 = bf16_rne(g1), gh2 = bf16_rne(g2);
    const unsigned short gl0 = bf16_rne(g0 - bf16_f32(gh0));
    const unsigned short gl1 = bf16_rne(g1 - bf16_f32(gh1));
    const unsigned short gl2 = bf16_rne(g2 - bf16_f32(gh2));
    int4 clo, chi;
    clo.x = pack2(gh0, gh1); clo.y = pack2(gh2, gl0);
    clo.z = pack2(gl1, gl2); clo.w = pack2(gh0, gh1);
    chi.x = pack2(gh2, sh);  chi.y = pack2(sl, one);
    chi.z = pack2(one, 0u);  chi.w = 0;
    colpack[2 * id]     = clo;
    colpack[2 * id + 1] = chi;
}

__device__ inline float red16(float cb, const f32x16& d) {
    const float m0 = fminf(fminf(d[0],  d[1]),  d[2]);
    const float m1 = fminf(fminf(d[3],  d[4]),  d[5]);
    const float m2 = fminf(fminf(d[6],  d[7]),  d[8]);
    const float m3 = fminf(fminf(d[9],  d[10]), d[11]);
    const float m4 = fminf(fminf(d[12], d[13]), d[14]);
    const float u0 = fminf(fminf(m0, m1), m2);
    const float u1 = fminf(fminf(m3, m4), d[15]);
    return fminf(fminf(cb, u0), u1);
}

__global__ __launch_bounds__(TPB, 8) void chamfer_main(
    const int4* __restrict__ rowpack,
    const int4* __restrict__ colpack,
    unsigned int* __restrict__ keys)
{
    const int blk  = blockIdx.x;
    const int seg  = blk & (YSEGS - 1);
    const int xblk = (blk >> 3) & (XBLKS - 1);
    const int b    = (blk >> 8) & (BATCH - 1);
    const int dir  = blk >> 10;
    const int arrB = dir;        // cols = array whose dist we output
    const int arrA = dir ^ 1;    // rows = the other array, streamed

    const int t = threadIdx.x, lane = t & 63, wave = t >> 6;
    const int half = lane >> 5, l31 = lane & 31;

    __shared__ int4 sb0[CHUNK];   // half0 row-frags
    __shared__ int4 sb1[CHUNK];   // half1 row-frags

    // fixed B fragments: 2 x-col tiles per wave
    const int xbase = xblk * COLS_PER_BLOCK + wave * COLS_PER_WAVE;
    const size_t cb_idx = ((size_t)(arrB * BATCH + b) * NPTS + xbase) * 2;
    FragU bf0, bf1;
    bf0.i4 = colpack[cb_idx + (size_t)(0 * 32 + l31) * 2 + half];
    bf1.i4 = colpack[cb_idx + (size_t)(1 * 32 + l31) * 2 + half];

    float cb[NFRAG];
#pragma unroll
    for (int f = 0; f < NFRAG; ++f) cb[f] = __builtin_inff();
    const f32x16 zero = {0.0f, 0.0f, 0.0f, 0.0f, 0.0f, 0.0f, 0.0f, 0.0f,
                         0.0f, 0.0f, 0.0f, 0.0f, 0.0f, 0.0f, 0.0f, 0.0f};

    const size_t rbase = ((size_t)(arrA * BATCH + b) * NPTS + (size_t)seg * YSEG) * 2;

    for (int c = 0; c < NCHUNK; ++c) {
        __syncthreads();
        {
            // copy 512 prepacked row-frags (2 pts / thread, 64B coalesced)
            const int4* src = rowpack + rbase + (size_t)c * CHUNK * 2 + (size_t)t * 4;
            const int4 a0 = src[0], a1 = src[1], a2 = src[2], a3 = src[3];
            sb0[2 * t]     = a0;  sb1[2 * t]     = a1;
            sb0[2 * t + 1] = a2;  sb1[2 * t + 1] = a3;
        }
        __syncthreads();

        const int4* asrc = half ? sb1 : sb0;
#pragma unroll 4
        for (int jt = 0; jt < JT; ++jt) {
            FragU af; af.i4 = asrc[jt * 32 + l31];
            f32x16 d0 = __builtin_amdgcn_mfma_f32_32x32x16_bf16(af.v, bf0.v, zero, 0, 0, 0);
            f32x16 d1 = __builtin_amdgcn_mfma_f32_32x32x16_bf16(af.v, bf1.v, zero, 0, 0, 0);
            // pin results to arch VGPRs so min3 doesn't round-trip AGPRs
            asm volatile("" :: "v"(d0), "v"(d1));
            cb[0] = red16(cb[0], d0);
            cb[1] = red16(cb[1], d1);
        }
    }

    // epilogue: combine the two halves (same cols), one atomic per frag
    unsigned int* ok = keys + ((size_t)dir * BATCH + b) * NPTS + xbase;
#pragma unroll
    for (int f = 0; f < NFRAG; ++f) {
        const float v = fminf(cb[f], __shfl_xor(cb[f], 32, 64));
        if (half == 0) {
            const unsigned int u = __float_as_uint(v);
            const unsigned int key = u ^ ((u >> 31) ? 0xFFFFFFFFu : 0x80000000u);
            atomicMin(&ok[f * 32 + l31], key);
        }
    }
}

__device__ inline float key_decode(unsigned int key) {
    const unsigned int u = (key & 0x80000000u) ? (key ^ 0x80000000u) : ~key;
    return __uint_as_float(u);
}

// 8 blocks x 1024 threads; each thread owns one uint4 of each direction.
// Partials go through device-scope atomics (coherent point, XCD-safe);
// last block to increment the counter sums partials in fixed order.
__global__ __launch_bounds__(1024) void reduce_kernel(
    const unsigned int* __restrict__ keys,
    unsigned long long* __restrict__ partials,   // 16 slots
    unsigned int* __restrict__ counter,
    float* __restrict__ out)
{
    const uint4* v1 = (const uint4*)keys;                    // dir 0
    const uint4* v2 = (const uint4*)(keys + BATCH * NPTS);   // dir 1
    const int idx = blockIdx.x * 1024 + threadIdx.x;         // [0, 8192)
    const uint4 a = v1[idx];
    const uint4 c = v2[idx];
    double s1 = (double)key_decode(a.x) + (double)key_decode(a.y)
              + (double)key_decode(a.z) + (double)key_decode(a.w);
    double s2 = (double)key_decode(c.x) + (double)key_decode(c.y)
              + (double)key_decode(c.z) + (double)key_decode(c.w);
    for (int off = 32; off > 0; off >>= 1) {
        s1 += __shfl_down(s1, off, 64);
        s2 += __shfl_down(s2, off, 64);
    }
    __shared__ double l1[16], l2[16];
    const int wave = threadIdx.x >> 6;
    if ((threadIdx.x & 63) == 0) { l1[wave] = s1; l2[wave] = s2; }
    __syncthreads();
    if (threadIdx.x == 0) {
        double t1 = 0.0, t2 = 0.0;
        for (int w = 0; w < 16; ++w) { t1 += l1[w]; t2 += l2[w]; }
        atomicExch(&partials[2 * blockIdx.x],     (unsigned long long)__double_as_longlong(t1));
        atomicExch(&partials[2 * blockIdx.x + 1], (unsigned long long)__double_as_longlong(t2));
        __threadfence();
        const unsigned int old = atomicAdd(counter, 1u);
        if (old == 7u) {   // last block: finalize in fixed order (deterministic)
            double g1 = 0.0, g2 = 0.0;
            for (int w = 0; w < 8; ++w) {
                g1 += __longlong_as_double((long long)atomicAdd(&partials[2 * w],     0ull));
                g2 += __longlong_as_double((long long)atomicAdd(&partials[2 * w + 1], 0ull));
            }
            const double n = (double)(BATCH * NPTS);
            out[0] = (float)(g1 / n + g2 / n);
        }
    }
}

extern "C" void kernel_launch(void* const* d_in, const int* in_sizes, int n_in,
                              void* d_out, int out_size, void* d_ws, size_t ws_size,
                              hipStream_t stream) {
    const float* xyz1 = (const float*)d_in[0];
    const float* xyz2 = (const float*)d_in[1];
    float* out = (float*)d_out;

    int4* rowpack = (int4*)d_ws;                                  // 2 MB
    int4* colpack = rowpack + 2 * 65536;                          // 2 MB
    unsigned int* keys = (unsigned int*)(colpack + 2 * 65536);    // 256 KB
    unsigned long long* partials = (unsigned long long*)(keys + 2 * BATCH * NPTS);
    unsigned int* counter = (unsigned int*)(partials + 16);

    prepack_kernel<<<256, 256, 0, stream>>>(xyz1, xyz2, rowpack, colpack, keys, counter);

    chamfer_main<<<2 * BATCH * XBLKS * YSEGS, TPB, 0, stream>>>(rowpack, colpack, keys);

    reduce_kernel<<<8, 1024, 0, stream>>>(keys, partials, counter, out);
}